// Round 3
// baseline (272.940 us; speedup 1.0000x reference)
//
#include <hip/hip_runtime.h>

typedef short short8 __attribute__((ext_vector_type(8)));
typedef float f32x4 __attribute__((ext_vector_type(4)));
typedef unsigned short ushort_t;

__device__ inline ushort_t f2bf(float f) {
    union { float f; unsigned int u; } x{f};
    unsigned int r = (x.u + 0x7fffu + ((x.u >> 16) & 1u)) >> 16;
    return (ushort_t)r;
}

// ---------- kernel 0: W [1024][128] f32 -> Wt [128][1024] bf16 (x3) ----------
__global__ __launch_bounds__(1024) void wt_prep(const float* __restrict__ Wq,
                                                const float* __restrict__ Wk,
                                                const float* __restrict__ Wv,
                                                ushort_t* __restrict__ Wt) {
    __shared__ float t[32][33];
    int bz = blockIdx.z;
    const float* W = bz == 0 ? Wq : (bz == 1 ? Wk : Wv);
    int h0 = blockIdx.x * 32, c0 = blockIdx.y * 32;
    int tx = threadIdx.x, ty = threadIdx.y;
    t[ty][tx] = W[(c0 + ty) * 128 + h0 + tx];
    __syncthreads();
    Wt[bz * 131072 + (h0 + ty) * 1024 + c0 + tx] = f2bf(t[tx][ty]);
}

// ---------- kernel 1: X [16384][1024] f32 @ Wt^T -> bf16 Q/K (row-major), V (transposed per batch) ----------
__global__ __launch_bounds__(256) void proj_gemm(const float* __restrict__ q,
                                                 const float* __restrict__ k,
                                                 const float* __restrict__ v,
                                                 const ushort_t* __restrict__ Wt,
                                                 ushort_t* __restrict__ Qb,
                                                 ushort_t* __restrict__ Kb,
                                                 ushort_t* __restrict__ Vt) {
    __shared__ ushort_t lA[128][72];   // [row][k] bf16, stride 144B (bank-friendly)
    __shared__ ushort_t lB[128][72];   // [h][k]  bf16
    int z = blockIdx.z;
    const float* X = z == 0 ? q : (z == 1 ? k : v);
    const ushort_t* Wz = Wt + z * 131072;
    int m0 = blockIdx.x * 128;
    int tid = threadIdx.x;
    int lane = tid & 63, wv = tid >> 6;
    int g = lane >> 4, li = lane & 15;

    f32x4 z4 = {0.f, 0.f, 0.f, 0.f};
    f32x4 acc[2][8];
#pragma unroll
    for (int m = 0; m < 2; ++m)
#pragma unroll
        for (int n = 0; n < 8; ++n) acc[m][n] = z4;

    for (int ks = 0; ks < 16; ++ks) {
        int k0 = ks * 64;
        if (ks) __syncthreads();
        // stage A: 128x64 fp32 -> bf16, coalesced float4 loads
#pragma unroll
        for (int it = 0; it < 8; ++it) {
            int idx = it * 256 + tid;
            int row = idx >> 4, c4 = idx & 15;
            const float4 val = *(const float4*)(X + (size_t)(m0 + row) * 1024 + k0 + c4 * 4);
            ushort4 bb;
            bb.x = f2bf(val.x); bb.y = f2bf(val.y); bb.z = f2bf(val.z); bb.w = f2bf(val.w);
            *(ushort4*)&lA[row][c4 * 4] = bb;
        }
        // stage B: Wt rows (bf16), 16B copies
#pragma unroll
        for (int it = 0; it < 4; ++it) {
            int idx = it * 256 + tid;
            int h = idx >> 3, k8 = idx & 7;
            *(int4*)&lB[h][k8 * 8] = *(const int4*)(Wz + h * 1024 + k0 + k8 * 8);
        }
        __syncthreads();
#pragma unroll
        for (int kk = 0; kk < 2; ++kk) {
            short8 a[2], b[8];
#pragma unroll
            for (int m = 0; m < 2; ++m)
                a[m] = *(const short8*)&lA[wv * 32 + m * 16 + li][kk * 32 + g * 8];
#pragma unroll
            for (int n = 0; n < 8; ++n)
                b[n] = *(const short8*)&lB[n * 16 + li][kk * 32 + g * 8];
#pragma unroll
            for (int m = 0; m < 2; ++m)
#pragma unroll
                for (int n = 0; n < 8; ++n)
                    acc[m][n] = __builtin_amdgcn_mfma_f32_16x16x32_bf16(a[m], b[n], acc[m][n], 0, 0, 0);
        }
    }
    // epilogue: D layout col=lane&15, row=(lane>>4)*4+reg
    if (z < 2) {
        ushort_t* Out = z == 0 ? Qb : Kb;
#pragma unroll
        for (int m = 0; m < 2; ++m) {
            int rbase = m0 + wv * 32 + m * 16 + g * 4;
#pragma unroll
            for (int n = 0; n < 8; ++n)
#pragma unroll
                for (int r = 0; r < 4; ++r)
                    Out[(size_t)(rbase + r) * 128 + n * 16 + li] = f2bf(acc[m][n][r]);
        }
    } else {
#pragma unroll
        for (int m = 0; m < 2; ++m) {
            int tbase = m0 + wv * 32 + m * 16 + g * 4;
#pragma unroll
            for (int n = 0; n < 8; ++n)
#pragma unroll
                for (int r = 0; r < 4; ++r) {
                    int t = tbase + r;
                    int bb = t >> 11, tl = t & 2047;
                    Vt[((size_t)bb * 128 + n * 16 + li) * 2048 + tl] = f2bf(acc[m][n][r]);
                }
        }
    }
}

// ---------- kernel 2: flash attention, causal (j <= i+1), per-wave independent ----------
__global__ __launch_bounds__(256) void attn_fwd(const ushort_t* __restrict__ Qb,
                                                const ushort_t* __restrict__ Kb,
                                                const ushort_t* __restrict__ Vt,
                                                float* __restrict__ Out) {
    constexpr float SCL = 0.08838834764831845f * 1.4426950408889634f; // 1/sqrt(128) * log2(e)
    __shared__ ushort_t lP[4][16][72];   // per-wave private P tile
    int tid = threadIdx.x;
    int lane = tid & 63, wv = tid >> 6;
    int g = lane >> 4, li = lane & 15;
    int b = blockIdx.x >> 5;                     // batch
    int rt = (blockIdx.x & 31) * 4 + wv;         // adjacent row-tiles per block -> L1/L2 K/V reuse
    int r0 = rt * 16;
    ushort_t (*P)[72] = lP[wv];

    // Q fragments: lane holds Q[r0 + (l&15)][kf*32 + (l>>4)*8 + 0..7]
    short8 qf[4];
    const ushort_t* qrow = Qb + (size_t)(b * 2048 + r0 + li) * 128 + g * 8;
#pragma unroll
    for (int kf = 0; kf < 4; ++kf) qf[kf] = *(const short8*)(qrow + kf * 32);

    f32x4 z4 = {0.f, 0.f, 0.f, 0.f};
    f32x4 o[8];
#pragma unroll
    for (int n = 0; n < 8; ++n) o[n] = z4;
    float mr[4], lr[4];
#pragma unroll
    for (int r = 0; r < 4; ++r) { mr[r] = -1e30f; lr[r] = 0.f; }

    int NT = (r0 + 80) >> 6;           // ceil((r0+17)/64)
    if (NT > 32) NT = 32;
    const ushort_t* kb0 = Kb + (size_t)b * 2048 * 128;
    const ushort_t* vb0 = Vt + (size_t)b * 128 * 2048;

    for (int jt = 0; jt < NT; ++jt) {
        int j0 = jt * 64;
        f32x4 s[4];
#pragma unroll
        for (int jf = 0; jf < 4; ++jf) s[jf] = z4;
        // S = Q K^T : B-frag lane holds K[j0+jf*16+(l&15)][k contiguous 8]
#pragma unroll
        for (int jf = 0; jf < 4; ++jf) {
            const ushort_t* krow = kb0 + (size_t)(j0 + jf * 16 + li) * 128 + g * 8;
#pragma unroll
            for (int kf = 0; kf < 4; ++kf) {
                short8 kfrag = *(const short8*)(krow + kf * 32);
                s[jf] = __builtin_amdgcn_mfma_f32_16x16x32_bf16(qf[kf], kfrag, s[jf], 0, 0, 0);
            }
        }
        // causal mask: disallow j > i+1 (only needed near diagonal)
        if (j0 + 63 > r0 + 1) {
#pragma unroll
            for (int jf = 0; jf < 4; ++jf)
#pragma unroll
                for (int r = 0; r < 4; ++r) {
                    int j = j0 + jf * 16 + li;
                    int i = r0 + g * 4 + r;
                    if (j > i + 1) s[jf][r] = -1e30f;
                }
        }
        // row max over 64 cols: 4 frags in-lane + butterfly over 16-lane group
        float mt[4];
#pragma unroll
        for (int r = 0; r < 4; ++r)
            mt[r] = fmaxf(fmaxf(s[0][r], s[1][r]), fmaxf(s[2][r], s[3][r]));
#pragma unroll
        for (int d = 1; d < 16; d <<= 1)
#pragma unroll
            for (int r = 0; r < 4; ++r)
                mt[r] = fmaxf(mt[r], __shfl_xor(mt[r], d));
        float al[4];
#pragma unroll
        for (int r = 0; r < 4; ++r) {
            float mn = fmaxf(mr[r], mt[r]);
            al[r] = exp2f((mr[r] - mn) * SCL);
            mr[r] = mn;
        }
        // P = exp2((S-m)*SCL): accumulate row sum + spill bf16 P to per-wave LDS
        float rs[4] = {0.f, 0.f, 0.f, 0.f};
#pragma unroll
        for (int jf = 0; jf < 4; ++jf)
#pragma unroll
            for (int r = 0; r < 4; ++r) {
                float p = exp2f((s[jf][r] - mr[r]) * SCL);
                rs[r] += p;
                P[g * 4 + r][jf * 16 + li] = f2bf(p);
            }
#pragma unroll
        for (int d = 1; d < 16; d <<= 1)
#pragma unroll
            for (int r = 0; r < 4; ++r)
                rs[r] += __shfl_xor(rs[r], d);
#pragma unroll
        for (int r = 0; r < 4; ++r) lr[r] = lr[r] * al[r] + rs[r];
#pragma unroll
        for (int n = 0; n < 8; ++n)
#pragma unroll
            for (int r = 0; r < 4; ++r) o[n][r] *= al[r];
        // cross-lane RAW through LDS within the wave: drain DS queue before reads
        asm volatile("s_waitcnt lgkmcnt(0)" ::: "memory");
        __builtin_amdgcn_sched_barrier(0);
        // O += P V : A-frag from LDS P, B-frag contiguous from Vt[o][j]
#pragma unroll
        for (int kk = 0; kk < 2; ++kk) {
            short8 pa = *(const short8*)&P[li][kk * 32 + g * 8];
#pragma unroll
            for (int n = 0; n < 8; ++n) {
                short8 vfrag = *(const short8*)(vb0 + (size_t)(n * 16 + li) * 2048 + j0 + kk * 32 + g * 8);
                o[n] = __builtin_amdgcn_mfma_f32_16x16x32_bf16(pa, vfrag, o[n], 0, 0, 0);
            }
        }
    }
    // epilogue: fp32, coalesced 4B stores
#pragma unroll
    for (int n = 0; n < 8; ++n)
#pragma unroll
        for (int r = 0; r < 4; ++r) {
            int i = r0 + g * 4 + r;
            Out[(size_t)(b * 2048 + i) * 128 + n * 16 + li] = o[n][r] / lr[r];
        }
}

extern "C" void kernel_launch(void* const* d_in, const int* in_sizes, int n_in,
                              void* d_out, int out_size, void* d_ws, size_t ws_size,
                              hipStream_t stream) {
    const float* q  = (const float*)d_in[0];
    const float* k  = (const float*)d_in[1];
    const float* v  = (const float*)d_in[2];
    const float* Wq = (const float*)d_in[3];
    const float* Wk = (const float*)d_in[4];
    const float* Wv = (const float*)d_in[5];
    float* Out = (float*)d_out;

    ushort_t* Qb = (ushort_t*)d_ws;          // [16384][128] bf16
    ushort_t* Kb = Qb + 2097152;             // [16384][128] bf16
    ushort_t* Vt = Kb + 2097152;             // [8][128][2048] bf16 (V transposed per batch)
    ushort_t* Wt = Vt + 2097152;             // [3][128][1024] bf16 (weights transposed)

    wt_prep<<<dim3(4, 32, 3), dim3(32, 32), 0, stream>>>(Wq, Wk, Wv, Wt);
    proj_gemm<<<dim3(128, 1, 3), 256, 0, stream>>>(q, k, v, Wt, Qb, Kb, Vt);
    attn_fwd<<<dim3(256), 256, 0, stream>>>(Qb, Kb, Vt, Out);
}

// Round 4
// 151.709 us; speedup vs baseline: 1.7991x; 1.7991x over previous
//
#include <hip/hip_runtime.h>

typedef short short8 __attribute__((ext_vector_type(8)));
typedef float f32x4 __attribute__((ext_vector_type(4)));
typedef unsigned short ushort_t;

__device__ inline ushort_t f2bf(float f) {
    union { float f; unsigned int u; } x{f};
    unsigned int r = (x.u + 0x7fffu + ((x.u >> 16) & 1u)) >> 16;
    return (ushort_t)r;
}

__device__ inline void gload_lds16(const void* g, void* l) {
    __builtin_amdgcn_global_load_lds(
        (const __attribute__((address_space(1))) unsigned int*)g,
        (__attribute__((address_space(3))) unsigned int*)l, 16, 0, 0);
}

template <int CTRL>
__device__ inline float dppmax(float x) {
    union { float f; int i; } u, v;
    u.f = x;
    v.i = __builtin_amdgcn_update_dpp(0, u.i, CTRL, 0xf, 0xf, true);
    return fmaxf(x, v.f);
}
template <int CTRL>
__device__ inline float dppadd(float x) {
    union { float f; int i; } u, v;
    u.f = x;
    v.i = __builtin_amdgcn_update_dpp(0, u.i, CTRL, 0xf, 0xf, true);
    return x + v.f;
}
// 16-lane reduction ctrls: xor1=quad_perm[1,0,3,2], xor2=quad_perm[2,3,0,1],
// then row_half_mirror (0x141), row_mirror (0x140).
#define DPP_XOR1 0xB1
#define DPP_XOR2 0x4E
#define DPP_HMIR 0x141
#define DPP_MIR  0x140

// ---------- kernel 0: W [1024][128] f32 -> Wt [128][1024] bf16 (x3) ----------
__global__ __launch_bounds__(1024) void wt_prep(const float* __restrict__ Wq,
                                                const float* __restrict__ Wk,
                                                const float* __restrict__ Wv,
                                                ushort_t* __restrict__ Wt) {
    __shared__ float t[32][33];
    int bz = blockIdx.z;
    const float* W = bz == 0 ? Wq : (bz == 1 ? Wk : Wv);
    int h0 = blockIdx.x * 32, c0 = blockIdx.y * 32;
    int tx = threadIdx.x, ty = threadIdx.y;
    t[ty][tx] = W[(c0 + ty) * 128 + h0 + tx];
    __syncthreads();
    Wt[bz * 131072 + (h0 + ty) * 1024 + c0 + tx] = f2bf(t[tx][ty]);
}

// ---------- kernel 1: X [16384][1024] f32 @ Wt^T -> bf16 Q/K (row-major), V (transposed per batch) ----------
__global__ __launch_bounds__(256) void proj_gemm(const float* __restrict__ q,
                                                 const float* __restrict__ k,
                                                 const float* __restrict__ v,
                                                 const ushort_t* __restrict__ Wt,
                                                 ushort_t* __restrict__ Qb,
                                                 ushort_t* __restrict__ Kb,
                                                 ushort_t* __restrict__ Vt) {
    __shared__ ushort_t lA[128][72];
    __shared__ ushort_t lB[128][72];
    int z = blockIdx.z;
    const float* X = z == 0 ? q : (z == 1 ? k : v);
    const ushort_t* Wz = Wt + z * 131072;
    int m0 = blockIdx.x * 128;
    int tid = threadIdx.x;
    int lane = tid & 63, wv = tid >> 6;
    int g = lane >> 4, li = lane & 15;

    f32x4 z4 = {0.f, 0.f, 0.f, 0.f};
    f32x4 acc[2][8];
#pragma unroll
    for (int m = 0; m < 2; ++m)
#pragma unroll
        for (int n = 0; n < 8; ++n) acc[m][n] = z4;

    for (int ks = 0; ks < 16; ++ks) {
        int k0 = ks * 64;
        if (ks) __syncthreads();
#pragma unroll
        for (int it = 0; it < 8; ++it) {
            int idx = it * 256 + tid;
            int row = idx >> 4, c4 = idx & 15;
            const float4 val = *(const float4*)(X + (size_t)(m0 + row) * 1024 + k0 + c4 * 4);
            ushort4 bb;
            bb.x = f2bf(val.x); bb.y = f2bf(val.y); bb.z = f2bf(val.z); bb.w = f2bf(val.w);
            *(ushort4*)&lA[row][c4 * 4] = bb;
        }
#pragma unroll
        for (int it = 0; it < 4; ++it) {
            int idx = it * 256 + tid;
            int h = idx >> 3, k8 = idx & 7;
            *(int4*)&lB[h][k8 * 8] = *(const int4*)(Wz + h * 1024 + k0 + k8 * 8);
        }
        __syncthreads();
#pragma unroll
        for (int kk = 0; kk < 2; ++kk) {
            short8 a[2], b[8];
#pragma unroll
            for (int m = 0; m < 2; ++m)
                a[m] = *(const short8*)&lA[wv * 32 + m * 16 + li][kk * 32 + g * 8];
#pragma unroll
            for (int n = 0; n < 8; ++n)
                b[n] = *(const short8*)&lB[n * 16 + li][kk * 32 + g * 8];
#pragma unroll
            for (int m = 0; m < 2; ++m)
#pragma unroll
                for (int n = 0; n < 8; ++n)
                    acc[m][n] = __builtin_amdgcn_mfma_f32_16x16x32_bf16(a[m], b[n], acc[m][n], 0, 0, 0);
        }
    }
    if (z < 2) {
        ushort_t* Out = z == 0 ? Qb : Kb;
#pragma unroll
        for (int m = 0; m < 2; ++m) {
            int rbase = m0 + wv * 32 + m * 16 + g * 4;
#pragma unroll
            for (int n = 0; n < 8; ++n)
#pragma unroll
                for (int r = 0; r < 4; ++r)
                    Out[(size_t)(rbase + r) * 128 + n * 16 + li] = f2bf(acc[m][n][r]);
        }
    } else {
#pragma unroll
        for (int m = 0; m < 2; ++m) {
            int tbase = m0 + wv * 32 + m * 16 + g * 4;
#pragma unroll
            for (int n = 0; n < 8; ++n)
#pragma unroll
                for (int r = 0; r < 4; ++r) {
                    int t = tbase + r;
                    int bb = t >> 11, tl = t & 2047;
                    Vt[((size_t)bb * 128 + n * 16 + li) * 2048 + tl] = f2bf(acc[m][n][r]);
                }
        }
    }
}

// ---------- kernel 2: flash attention, causal (j <= i+1) ----------
// 128 threads = 2 waves; QBLK=32 (16 rows/wave), KVBLK=32.
// K/V double-buffered in LDS via global_load_lds (linear dest, inverse-swizzled
// source, swizzled ds_read). 2-phase pipeline: counted vmcnt(8) + raw barriers.
__global__ __launch_bounds__(128) void attn_fwd(const ushort_t* __restrict__ Qb,
                                                const ushort_t* __restrict__ Kb,
                                                const ushort_t* __restrict__ Vt,
                                                float* __restrict__ Out) {
    constexpr float SCL = 0.08838834764831845f * 1.4426950408889634f; // 1/sqrt(128)*log2(e)
    __shared__ ushort_t Kl[2][32][128];   // [buf][j][k]  8KB/buf, row=256B
    __shared__ ushort_t Vl[2][128][32];   // [buf][d][j]  8KB/buf, row=64B
    __shared__ ushort_t lP[2][16][72];    // per-wave private P tile
    int t = threadIdx.x;
    int lane = t & 63, wv = t >> 6;
    int g = lane >> 4, li = lane & 15;
    int b = blockIdx.x >> 6;
    int qb = 63 - (blockIdx.x & 63);      // longest blocks dispatch first
    int r0 = qb * 32 + wv * 16;
    int NT = qb + 2; if (NT > 64) NT = 64;
    const ushort_t* kb0 = Kb + (size_t)b * 2048 * 128;
    const ushort_t* vb0 = Vt + (size_t)b * 128 * 2048;
    ushort_t (*P)[72] = lP[wv];

    short8 qf[4];
    const ushort_t* qrow = Qb + (size_t)(b * 2048 + r0 + li) * 128 + g * 8;
#pragma unroll
    for (int kf = 0; kf < 4; ++kf) qf[kf] = *(const short8*)(qrow + kf * 32);

    f32x4 z4 = {0.f, 0.f, 0.f, 0.f};
    f32x4 o[8];
#pragma unroll
    for (int n = 0; n < 8; ++n) o[n] = z4;
    float mr[4], lr[4];
#pragma unroll
    for (int r = 0; r < 4; ++r) { mr[r] = -1e30f; lr[r] = 0.f; }

    auto STAGE = [&](int jt, int buf) {
        int j0 = jt * 32;
        // K tile: 4 rounds x 2KB. LDS[row][c16] holds global chunk c16^(row&7).
#pragma unroll
        for (int r = 0; r < 4; ++r) {
            int row = r * 8 + (t >> 4);
            int c16 = (t & 15) ^ (row & 7);
            gload_lds16(kb0 + (size_t)(j0 + row) * 128 + c16 * 8,
                        (char*)&Kl[buf][0][0] + r * 2048 + t * 16);
        }
        // V tile: 4 rounds. LDS[d][c16] holds global chunk c16^(d&3).
#pragma unroll
        for (int r = 0; r < 4; ++r) {
            int row = r * 32 + (t >> 2);
            int c16 = (t & 3) ^ (row & 3);
            gload_lds16(vb0 + (size_t)row * 2048 + j0 + c16 * 8,
                        (char*)&Vl[buf][0][0] + r * 2048 + t * 16);
        }
    };

    STAGE(0, 0);
    for (int jt = 0; jt < NT; ++jt) {
        int buf = jt & 1;
        int j0 = jt * 32;
        __builtin_amdgcn_s_barrier();          // all done reading buf^1 (prev-prev tile)
        if (jt + 1 < NT) {
            STAGE(jt + 1, buf ^ 1);
            asm volatile("s_waitcnt vmcnt(8)" ::: "memory");   // tile jt's 8 loads done
        } else {
            asm volatile("s_waitcnt vmcnt(0)" ::: "memory");
        }
        __builtin_amdgcn_sched_barrier(0);
        __builtin_amdgcn_s_barrier();          // buf[jt&1] ready for all waves
        __builtin_amdgcn_sched_barrier(0);

        const char* kb = (const char*)&Kl[buf][0][0];
        const char* vb = (const char*)&Vl[buf][0][0];
        f32x4 s[2];
        s[0] = z4; s[1] = z4;
#pragma unroll
        for (int jf = 0; jf < 2; ++jf)
#pragma unroll
            for (int kf = 0; kf < 4; ++kf) {
                short8 kfrag = *(const short8*)(kb + (jf * 16 + li) * 256 +
                                                (((kf * 4 + g) ^ (li & 7)) * 16));
                s[jf] = __builtin_amdgcn_mfma_f32_16x16x32_bf16(qf[kf], kfrag, s[jf], 0, 0, 0);
            }
        if (j0 + 31 > r0 + 1) {
#pragma unroll
            for (int jf = 0; jf < 2; ++jf)
#pragma unroll
                for (int r = 0; r < 4; ++r) {
                    int j = j0 + jf * 16 + li;
                    int i = r0 + g * 4 + r;
                    if (j > i + 1) s[jf][r] = -1e30f;
                }
        }
        float mt[4];
#pragma unroll
        for (int r = 0; r < 4; ++r) {
            mt[r] = fmaxf(s[0][r], s[1][r]);
            mt[r] = dppmax<DPP_XOR1>(mt[r]);
            mt[r] = dppmax<DPP_XOR2>(mt[r]);
            mt[r] = dppmax<DPP_HMIR>(mt[r]);
            mt[r] = dppmax<DPP_MIR>(mt[r]);
        }
        float al[4];
#pragma unroll
        for (int r = 0; r < 4; ++r) {
            float mn = fmaxf(mr[r], mt[r]);
            al[r] = exp2f((mr[r] - mn) * SCL);
            mr[r] = mn;
        }
        float rs[4] = {0.f, 0.f, 0.f, 0.f};
#pragma unroll
        for (int jf = 0; jf < 2; ++jf)
#pragma unroll
            for (int r = 0; r < 4; ++r) {
                float p = exp2f((s[jf][r] - mr[r]) * SCL);
                rs[r] += p;
                P[g * 4 + r][jf * 16 + li] = f2bf(p);
            }
#pragma unroll
        for (int r = 0; r < 4; ++r) {
            rs[r] = dppadd<DPP_XOR1>(rs[r]);
            rs[r] = dppadd<DPP_XOR2>(rs[r]);
            rs[r] = dppadd<DPP_HMIR>(rs[r]);
            rs[r] = dppadd<DPP_MIR>(rs[r]);
            lr[r] = lr[r] * al[r] + rs[r];
        }
#pragma unroll
        for (int n = 0; n < 8; ++n)
#pragma unroll
            for (int r = 0; r < 4; ++r) o[n][r] *= al[r];
        // wave-internal RAW through LDS P
        asm volatile("s_waitcnt lgkmcnt(0)" ::: "memory");
        __builtin_amdgcn_sched_barrier(0);
        short8 pa = *(const short8*)&P[li][g * 8];
#pragma unroll
        for (int n = 0; n < 8; ++n) {
            short8 vfrag = *(const short8*)(vb + (n * 16 + li) * 64 + ((g ^ (li & 3)) * 16));
            o[n] = __builtin_amdgcn_mfma_f32_16x16x32_bf16(pa, vfrag, o[n], 0, 0, 0);
        }
    }
#pragma unroll
    for (int n = 0; n < 8; ++n)
#pragma unroll
        for (int r = 0; r < 4; ++r) {
            int i = r0 + g * 4 + r;
            Out[(size_t)(b * 2048 + i) * 128 + n * 16 + li] = o[n][r] / lr[r];
        }
}

extern "C" void kernel_launch(void* const* d_in, const int* in_sizes, int n_in,
                              void* d_out, int out_size, void* d_ws, size_t ws_size,
                              hipStream_t stream) {
    const float* q  = (const float*)d_in[0];
    const float* k  = (const float*)d_in[1];
    const float* v  = (const float*)d_in[2];
    const float* Wq = (const float*)d_in[3];
    const float* Wk = (const float*)d_in[4];
    const float* Wv = (const float*)d_in[5];
    float* Out = (float*)d_out;

    ushort_t* Qb = (ushort_t*)d_ws;          // [16384][128] bf16
    ushort_t* Kb = Qb + 2097152;             // [16384][128] bf16
    ushort_t* Vt = Kb + 2097152;             // [8][128][2048] bf16
    ushort_t* Wt = Vt + 2097152;             // [3][128][1024] bf16

    wt_prep<<<dim3(4, 32, 3), dim3(32, 32), 0, stream>>>(Wq, Wk, Wv, Wt);
    proj_gemm<<<dim3(128, 1, 3), 256, 0, stream>>>(q, k, v, Wt, Qb, Kb, Vt);
    attn_fwd<<<dim3(512), 128, 0, stream>>>(Qb, Kb, Vt, Out);
}

// Round 5
// 128.372 us; speedup vs baseline: 2.1262x; 1.1818x over previous
//
#include <hip/hip_runtime.h>

typedef short short8 __attribute__((ext_vector_type(8)));
typedef float f32x4 __attribute__((ext_vector_type(4)));
typedef unsigned short ushort_t;

__device__ inline ushort_t f2bf(float f) {
    union { float f; unsigned int u; } x{f};
    unsigned int r = (x.u + 0x7fffu + ((x.u >> 16) & 1u)) >> 16;
    return (ushort_t)r;
}

template <int CTRL>
__device__ inline float dppmax(float x) {
    union { float f; int i; } u, v;
    u.f = x;
    v.i = __builtin_amdgcn_update_dpp(0, u.i, CTRL, 0xf, 0xf, true);
    return fmaxf(x, v.f);
}
template <int CTRL>
__device__ inline float dppadd(float x) {
    union { float f; int i; } u, v;
    u.f = x;
    v.i = __builtin_amdgcn_update_dpp(0, u.i, CTRL, 0xf, 0xf, true);
    return x + v.f;
}
#define DPP_XOR1 0xB1
#define DPP_XOR2 0x4E
#define DPP_HMIR 0x141
#define DPP_MIR  0x140

// ---------- kernel 0: W [1024][128] f32 -> Wt [128][1024] bf16 (x3) ----------
__global__ __launch_bounds__(1024) void wt_prep(const float* __restrict__ Wq,
                                                const float* __restrict__ Wk,
                                                const float* __restrict__ Wv,
                                                ushort_t* __restrict__ Wt) {
    __shared__ float t[32][33];
    int bz = blockIdx.z;
    const float* W = bz == 0 ? Wq : (bz == 1 ? Wk : Wv);
    int h0 = blockIdx.x * 32, c0 = blockIdx.y * 32;
    int tx = threadIdx.x, ty = threadIdx.y;
    t[ty][tx] = W[(c0 + ty) * 128 + h0 + tx];
    __syncthreads();
    Wt[bz * 131072 + (h0 + ty) * 1024 + c0 + tx] = f2bf(t[tx][ty]);
}

// ---------- kernel 1: X [16384][1024] f32 @ Wt^T -> bf16 Q/K (row-major), V (transposed per batch) ----------
__global__ __launch_bounds__(256) void proj_gemm(const float* __restrict__ q,
                                                 const float* __restrict__ k,
                                                 const float* __restrict__ v,
                                                 const ushort_t* __restrict__ Wt,
                                                 ushort_t* __restrict__ Qb,
                                                 ushort_t* __restrict__ Kb,
                                                 ushort_t* __restrict__ Vt) {
    __shared__ ushort_t lA[128][72];
    __shared__ ushort_t lB[128][72];
    int z = blockIdx.z;
    const float* X = z == 0 ? q : (z == 1 ? k : v);
    const ushort_t* Wz = Wt + z * 131072;
    int m0 = blockIdx.x * 128;
    int tid = threadIdx.x;
    int lane = tid & 63, wv = tid >> 6;
    int g = lane >> 4, li = lane & 15;

    f32x4 z4 = {0.f, 0.f, 0.f, 0.f};
    f32x4 acc[2][8];
#pragma unroll
    for (int m = 0; m < 2; ++m)
#pragma unroll
        for (int n = 0; n < 8; ++n) acc[m][n] = z4;

    for (int ks = 0; ks < 16; ++ks) {
        int k0 = ks * 64;
        if (ks) __syncthreads();
#pragma unroll
        for (int it = 0; it < 8; ++it) {
            int idx = it * 256 + tid;
            int row = idx >> 4, c4 = idx & 15;
            const float4 val = *(const float4*)(X + (size_t)(m0 + row) * 1024 + k0 + c4 * 4);
            ushort4 bb;
            bb.x = f2bf(val.x); bb.y = f2bf(val.y); bb.z = f2bf(val.z); bb.w = f2bf(val.w);
            *(ushort4*)&lA[row][c4 * 4] = bb;
        }
#pragma unroll
        for (int it = 0; it < 4; ++it) {
            int idx = it * 256 + tid;
            int h = idx >> 3, k8 = idx & 7;
            *(int4*)&lB[h][k8 * 8] = *(const int4*)(Wz + h * 1024 + k0 + k8 * 8);
        }
        __syncthreads();
#pragma unroll
        for (int kk = 0; kk < 2; ++kk) {
            short8 a[2], b[8];
#pragma unroll
            for (int m = 0; m < 2; ++m)
                a[m] = *(const short8*)&lA[wv * 32 + m * 16 + li][kk * 32 + g * 8];
#pragma unroll
            for (int n = 0; n < 8; ++n)
                b[n] = *(const short8*)&lB[n * 16 + li][kk * 32 + g * 8];
#pragma unroll
            for (int m = 0; m < 2; ++m)
#pragma unroll
                for (int n = 0; n < 8; ++n)
                    acc[m][n] = __builtin_amdgcn_mfma_f32_16x16x32_bf16(a[m], b[n], acc[m][n], 0, 0, 0);
        }
    }
    if (z < 2) {
        ushort_t* Out = z == 0 ? Qb : Kb;
#pragma unroll
        for (int m = 0; m < 2; ++m) {
            int rbase = m0 + wv * 32 + m * 16 + g * 4;
#pragma unroll
            for (int n = 0; n < 8; ++n)
#pragma unroll
                for (int r = 0; r < 4; ++r)
                    Out[(size_t)(rbase + r) * 128 + n * 16 + li] = f2bf(acc[m][n][r]);
        }
    } else {
#pragma unroll
        for (int m = 0; m < 2; ++m) {
            int tbase = m0 + wv * 32 + m * 16 + g * 4;
#pragma unroll
            for (int n = 0; n < 8; ++n)
#pragma unroll
                for (int r = 0; r < 4; ++r) {
                    int t = tbase + r;
                    int bb = t >> 11, tl = t & 2047;
                    Vt[((size_t)bb * 128 + n * 16 + li) * 2048 + tl] = f2bf(acc[m][n][r]);
                }
        }
    }
}

// ---------- kernel 2: flash attention, causal (j <= i+1), KV-split across 4 waves ----------
// Block = 4 waves, QBLK=16 shared rows. Wave w handles KV tiles {w, w+4, ...} (KVBLK=64)
// with private (m,l,o); LDS flash-merge at the end. K/V read direct from global (L2-resident;
// blockIdx%8 = batch -> one batch per XCD, 1MB K+V fits 4MB XCD L2). Longest qb first.
__global__ __launch_bounds__(256, 4) void attn_fwd(const ushort_t* __restrict__ Qb,
                                                   const ushort_t* __restrict__ Kb,
                                                   const ushort_t* __restrict__ Vt,
                                                   float* __restrict__ Out) {
    constexpr float SCL = 0.08838834764831845f * 1.4426950408889634f; // 1/sqrt(128)*log2(e)
    __shared__ char SMEM[34304];
    float (*oc)[16][132] = (float(*)[16][132])SMEM;          // [4][16][132] partial O (combine)
    float (*ml)[16][2]   = (float(*)[16][2])(SMEM + 33792);  // [4][16][2]  partial m,l
    ushort_t (*lP)[16][72] = (ushort_t(*)[16][72])SMEM;      // [4][16][72] P tiles (loop; aliases oc)

    int t = threadIdx.x;
    int lane = t & 63, wv = t >> 6;
    int g = lane >> 4, li = lane & 15;
    int b = blockIdx.x & 7;
    int qb = 127 - (blockIdx.x >> 3);     // longest spans dispatch first
    int r0 = qb * 16;
    int NT = (16 * qb + 81) >> 6;         // ceil((r0+18)/64)
    if (NT > 32) NT = 32;
    const ushort_t* kb0 = Kb + (size_t)b * 2048 * 128;
    const ushort_t* vb0 = Vt + (size_t)b * 128 * 2048;
    ushort_t (*P)[72] = lP[wv];

    short8 qf[4];
    const ushort_t* qrow = Qb + (size_t)(b * 2048 + r0 + li) * 128 + g * 8;
#pragma unroll
    for (int kf = 0; kf < 4; ++kf) qf[kf] = *(const short8*)(qrow + kf * 32);

    f32x4 z4 = {0.f, 0.f, 0.f, 0.f};
    f32x4 o[8];
#pragma unroll
    for (int n = 0; n < 8; ++n) o[n] = z4;
    float mr[4], lr[4];
#pragma unroll
    for (int r = 0; r < 4; ++r) { mr[r] = -1e30f; lr[r] = 0.f; }

    for (int jt = wv; jt < NT; jt += 4) {
        int j0 = jt * 64;
        f32x4 s[4];
#pragma unroll
        for (int jf = 0; jf < 4; ++jf) s[jf] = z4;
#pragma unroll
        for (int jf = 0; jf < 4; ++jf) {
            const ushort_t* krow = kb0 + (size_t)(j0 + jf * 16 + li) * 128 + g * 8;
#pragma unroll
            for (int kf = 0; kf < 4; ++kf) {
                short8 kfrag = *(const short8*)(krow + kf * 32);
                s[jf] = __builtin_amdgcn_mfma_f32_16x16x32_bf16(qf[kf], kfrag, s[jf], 0, 0, 0);
            }
        }
        if (j0 + 63 > r0 + 1) {
#pragma unroll
            for (int jf = 0; jf < 4; ++jf)
#pragma unroll
                for (int r = 0; r < 4; ++r) {
                    int j = j0 + jf * 16 + li;
                    int i = r0 + g * 4 + r;
                    if (j > i + 1) s[jf][r] = -1e30f;
                }
        }
        float mt[4];
#pragma unroll
        for (int r = 0; r < 4; ++r) {
            mt[r] = fmaxf(fmaxf(s[0][r], s[1][r]), fmaxf(s[2][r], s[3][r]));
            mt[r] = dppmax<DPP_XOR1>(mt[r]);
            mt[r] = dppmax<DPP_XOR2>(mt[r]);
            mt[r] = dppmax<DPP_HMIR>(mt[r]);
            mt[r] = dppmax<DPP_MIR>(mt[r]);
        }
        float al[4];
#pragma unroll
        for (int r = 0; r < 4; ++r) {
            float mn = fmaxf(mr[r], mt[r]);
            al[r] = exp2f((mr[r] - mn) * SCL);
            mr[r] = mn;
        }
        float rs[4] = {0.f, 0.f, 0.f, 0.f};
#pragma unroll
        for (int jf = 0; jf < 4; ++jf)
#pragma unroll
            for (int r = 0; r < 4; ++r) {
                float p = exp2f((s[jf][r] - mr[r]) * SCL);
                rs[r] += p;
                P[g * 4 + r][jf * 16 + li] = f2bf(p);
            }
#pragma unroll
        for (int r = 0; r < 4; ++r) {
            rs[r] = dppadd<DPP_XOR1>(rs[r]);
            rs[r] = dppadd<DPP_XOR2>(rs[r]);
            rs[r] = dppadd<DPP_HMIR>(rs[r]);
            rs[r] = dppadd<DPP_MIR>(rs[r]);
            lr[r] = lr[r] * al[r] + rs[r];
        }
#pragma unroll
        for (int n = 0; n < 8; ++n)
#pragma unroll
            for (int r = 0; r < 4; ++r) o[n][r] *= al[r];
        // wave-internal RAW through LDS P (rule 18: lgkmcnt + sched_barrier)
        asm volatile("s_waitcnt lgkmcnt(0)" ::: "memory");
        __builtin_amdgcn_sched_barrier(0);
#pragma unroll
        for (int kk = 0; kk < 2; ++kk) {
            short8 pa = *(const short8*)&P[li][kk * 32 + g * 8];
#pragma unroll
            for (int n = 0; n < 8; ++n) {
                short8 vfrag = *(const short8*)(vb0 + (size_t)(n * 16 + li) * 2048 + j0 + kk * 32 + g * 8);
                o[n] = __builtin_amdgcn_mfma_f32_16x16x32_bf16(pa, vfrag, o[n], 0, 0, 0);
            }
        }
    }

    __syncthreads();   // everyone done with lP region
#pragma unroll
    for (int n = 0; n < 8; ++n)
#pragma unroll
        for (int r = 0; r < 4; ++r)
            oc[wv][g * 4 + r][n * 16 + li] = o[n][r];
    if (li == 0) {
#pragma unroll
        for (int r = 0; r < 4; ++r) {
            ml[wv][g * 4 + r][0] = mr[r];
            ml[wv][g * 4 + r][1] = lr[r];
        }
    }
    __syncthreads();
    // combine: lane -> row li, cols wv*32 + g*8 + 0..7
    float m0 = ml[0][li][0], m1 = ml[1][li][0], m2 = ml[2][li][0], m3 = ml[3][li][0];
    float M = fmaxf(fmaxf(m0, m1), fmaxf(m2, m3));
    float E[4], L = 0.f;
#pragma unroll
    for (int w = 0; w < 4; ++w) {
        E[w] = exp2f((ml[w][li][0] - M) * SCL);
        L += ml[w][li][1] * E[w];
    }
    int c0 = wv * 32 + g * 8;
    float res[8];
#pragma unroll
    for (int c = 0; c < 8; ++c) {
        float a = 0.f;
#pragma unroll
        for (int w = 0; w < 4; ++w) a += oc[w][li][c0 + c] * E[w];
        res[c] = a / L;
    }
    float* op = Out + (size_t)(b * 2048 + r0 + li) * 128 + c0;
    float4 v0 = {res[0], res[1], res[2], res[3]};
    float4 v1 = {res[4], res[5], res[6], res[7]};
    *(float4*)op = v0;
    *(float4*)(op + 4) = v1;
}

extern "C" void kernel_launch(void* const* d_in, const int* in_sizes, int n_in,
                              void* d_out, int out_size, void* d_ws, size_t ws_size,
                              hipStream_t stream) {
    const float* q  = (const float*)d_in[0];
    const float* k  = (const float*)d_in[1];
    const float* v  = (const float*)d_in[2];
    const float* Wq = (const float*)d_in[3];
    const float* Wk = (const float*)d_in[4];
    const float* Wv = (const float*)d_in[5];
    float* Out = (float*)d_out;

    ushort_t* Qb = (ushort_t*)d_ws;          // [16384][128] bf16
    ushort_t* Kb = Qb + 2097152;             // [16384][128] bf16
    ushort_t* Vt = Kb + 2097152;             // [8][128][2048] bf16
    ushort_t* Wt = Vt + 2097152;             // [3][128][1024] bf16

    wt_prep<<<dim3(4, 32, 3), dim3(32, 32), 0, stream>>>(Wq, Wk, Wv, Wt);
    proj_gemm<<<dim3(128, 1, 3), 256, 0, stream>>>(q, k, v, Wt, Qb, Kb, Vt);
    attn_fwd<<<dim3(1024), 256, 0, stream>>>(Qb, Kb, Vt, Out);
}

// Round 7
// 122.808 us; speedup vs baseline: 2.2225x; 1.0453x over previous
//
#include <hip/hip_runtime.h>

typedef short short8 __attribute__((ext_vector_type(8)));
typedef float f32x4 __attribute__((ext_vector_type(4)));
typedef unsigned short ushort_t;

__device__ inline ushort_t f2bf(float f) {
    union { float f; unsigned int u; } x{f};
    unsigned int r = (x.u + 0x7fffu + ((x.u >> 16) & 1u)) >> 16;
    return (ushort_t)r;
}

template <int CTRL>
__device__ inline float dppmax(float x) {
    union { float f; int i; } u, v;
    u.f = x;
    v.i = __builtin_amdgcn_update_dpp(0, u.i, CTRL, 0xf, 0xf, true);
    return fmaxf(x, v.f);
}
template <int CTRL>
__device__ inline float dppadd(float x) {
    union { float f; int i; } u, v;
    u.f = x;
    v.i = __builtin_amdgcn_update_dpp(0, u.i, CTRL, 0xf, 0xf, true);
    return x + v.f;
}
#define DPP_XOR1 0xB1
#define DPP_XOR2 0x4E
#define DPP_HMIR 0x141
#define DPP_MIR  0x140

// ---------- kernel 0: W [1024][128] f32 -> Wt [128][1024] bf16 (x3) ----------
__global__ __launch_bounds__(1024) void wt_prep(const float* __restrict__ Wq,
                                                const float* __restrict__ Wk,
                                                const float* __restrict__ Wv,
                                                ushort_t* __restrict__ Wt) {
    __shared__ float t[32][33];
    int bz = blockIdx.z;
    const float* W = bz == 0 ? Wq : (bz == 1 ? Wk : Wv);
    int h0 = blockIdx.x * 32, c0 = blockIdx.y * 32;
    int tx = threadIdx.x, ty = threadIdx.y;
    t[ty][tx] = W[(c0 + ty) * 128 + h0 + tx];
    __syncthreads();
    Wt[bz * 131072 + (h0 + ty) * 1024 + c0 + tx] = f2bf(t[tx][ty]);
}

// ---------- kernel 1: X [16384][1024] f32 @ Wt^T -> bf16 Q/K (row-major), V (transposed) ----------
// BM=64, BN=128, BK=64; 256 threads = 4 waves, each wave owns 16 rows x 128 cols.
// grid = 256 m-tiles x 3  ->  3 blocks/CU, 4 resident (launch_bounds 256,4) -> latency
// hidden by cross-block overlap instead of intra-block pipelining.
__global__ __launch_bounds__(256, 4) void proj_gemm(const float* __restrict__ q,
                                                    const float* __restrict__ k,
                                                    const float* __restrict__ v,
                                                    const ushort_t* __restrict__ Wt,
                                                    ushort_t* __restrict__ Qb,
                                                    ushort_t* __restrict__ Kb,
                                                    ushort_t* __restrict__ Vt) {
    __shared__ ushort_t lA[64][72];    // 9.2 KB
    __shared__ ushort_t lB[128][72];   // 18.4 KB
    int z = blockIdx.z;
    const float* X = z == 0 ? q : (z == 1 ? k : v);
    const ushort_t* Wz = Wt + z * 131072;
    int m0 = blockIdx.x * 64;
    int tid = threadIdx.x;
    int lane = tid & 63, wv = tid >> 6;
    int g = lane >> 4, li = lane & 15;

    f32x4 z4 = {0.f, 0.f, 0.f, 0.f};
    f32x4 acc[8];
#pragma unroll
    for (int n = 0; n < 8; ++n) acc[n] = z4;

    for (int ks = 0; ks < 16; ++ks) {
        int k0 = ks * 64;
        if (ks) __syncthreads();
        // stage A: 64x64 fp32 -> bf16 (4 float4 loads/thread)
#pragma unroll
        for (int it = 0; it < 4; ++it) {
            int idx = it * 256 + tid;
            int row = idx >> 4, c4 = idx & 15;
            const float4 val = *(const float4*)(X + (size_t)(m0 + row) * 1024 + k0 + c4 * 4);
            ushort4 bb;
            bb.x = f2bf(val.x); bb.y = f2bf(val.y); bb.z = f2bf(val.z); bb.w = f2bf(val.w);
            *(ushort4*)&lA[row][c4 * 4] = bb;
        }
        // stage B: 128x64 bf16 (4 int4 copies/thread)
#pragma unroll
        for (int it = 0; it < 4; ++it) {
            int idx = it * 256 + tid;
            int h = idx >> 3, k8 = idx & 7;
            *(int4*)&lB[h][k8 * 8] = *(const int4*)(Wz + h * 1024 + k0 + k8 * 8);
        }
        __syncthreads();
#pragma unroll
        for (int kk = 0; kk < 2; ++kk) {
            short8 a = *(const short8*)&lA[wv * 16 + li][kk * 32 + g * 8];
            short8 b[8];
#pragma unroll
            for (int n = 0; n < 8; ++n)
                b[n] = *(const short8*)&lB[n * 16 + li][kk * 32 + g * 8];
#pragma unroll
            for (int n = 0; n < 8; ++n)
                acc[n] = __builtin_amdgcn_mfma_f32_16x16x32_bf16(a, b[n], acc[n], 0, 0, 0);
        }
    }
    // epilogue: D layout col=lane&15, row=(lane>>4)*4+reg
    if (z < 2) {
        ushort_t* Out = z == 0 ? Qb : Kb;
        int rbase = m0 + wv * 16 + g * 4;
#pragma unroll
        for (int n = 0; n < 8; ++n)
#pragma unroll
            for (int r = 0; r < 4; ++r)
                Out[(size_t)(rbase + r) * 128 + n * 16 + li] = f2bf(acc[n][r]);
    } else {
        int tbase = m0 + wv * 16 + g * 4;
#pragma unroll
        for (int n = 0; n < 8; ++n)
#pragma unroll
            for (int r = 0; r < 4; ++r) {
                int t = tbase + r;
                int bb = t >> 11, tl = t & 2047;
                Vt[((size_t)bb * 128 + n * 16 + li) * 2048 + tl] = f2bf(acc[n][r]);
            }
    }
}

// ---------- kernel 2: flash attention, causal (j <= i+1), KV-split across 4 waves ----------
__global__ __launch_bounds__(256, 4) void attn_fwd(const ushort_t* __restrict__ Qb,
                                                   const ushort_t* __restrict__ Kb,
                                                   const ushort_t* __restrict__ Vt,
                                                   float* __restrict__ Out) {
    constexpr float SCL = 0.08838834764831845f * 1.4426950408889634f; // 1/sqrt(128)*log2(e)
    __shared__ char SMEM[34304];
    float (*oc)[16][132] = (float(*)[16][132])SMEM;          // [4][16][132] partial O (combine)
    float (*ml)[16][2]   = (float(*)[16][2])(SMEM + 33792);  // [4][16][2]  partial m,l
    ushort_t (*lP)[16][72] = (ushort_t(*)[16][72])SMEM;      // [4][16][72] P tiles (aliases oc)

    int t = threadIdx.x;
    int lane = t & 63, wv = t >> 6;
    int g = lane >> 4, li = lane & 15;
    int b = blockIdx.x & 7;
    int qb = 127 - (blockIdx.x >> 3);     // longest spans dispatch first
    int r0 = qb * 16;
    int NT = (16 * qb + 81) >> 6;         // ceil((r0+18)/64)
    if (NT > 32) NT = 32;
    const ushort_t* kb0 = Kb + (size_t)b * 2048 * 128;
    const ushort_t* vb0 = Vt + (size_t)b * 128 * 2048;
    ushort_t (*P)[72] = lP[wv];

    short8 qf[4];
    const ushort_t* qrow = Qb + (size_t)(b * 2048 + r0 + li) * 128 + g * 8;
#pragma unroll
    for (int kf = 0; kf < 4; ++kf) qf[kf] = *(const short8*)(qrow + kf * 32);

    f32x4 z4 = {0.f, 0.f, 0.f, 0.f};
    f32x4 o[8];
#pragma unroll
    for (int n = 0; n < 8; ++n) o[n] = z4;
    float mr[4], lr[4];
#pragma unroll
    for (int r = 0; r < 4; ++r) { mr[r] = -1e30f; lr[r] = 0.f; }

    for (int jt = wv; jt < NT; jt += 4) {
        int j0 = jt * 64;
        f32x4 s[4];
#pragma unroll
        for (int jf = 0; jf < 4; ++jf) s[jf] = z4;
#pragma unroll
        for (int jf = 0; jf < 4; ++jf) {
            const ushort_t* krow = kb0 + (size_t)(j0 + jf * 16 + li) * 128 + g * 8;
#pragma unroll
            for (int kf = 0; kf < 4; ++kf) {
                short8 kfrag = *(const short8*)(krow + kf * 32);
                s[jf] = __builtin_amdgcn_mfma_f32_16x16x32_bf16(qf[kf], kfrag, s[jf], 0, 0, 0);
            }
        }
        if (j0 + 63 > r0 + 1) {
#pragma unroll
            for (int jf = 0; jf < 4; ++jf)
#pragma unroll
                for (int r = 0; r < 4; ++r) {
                    int j = j0 + jf * 16 + li;
                    int i = r0 + g * 4 + r;
                    if (j > i + 1) s[jf][r] = -1e30f;
                }
        }
        float mt[4];
#pragma unroll
        for (int r = 0; r < 4; ++r) {
            mt[r] = fmaxf(fmaxf(s[0][r], s[1][r]), fmaxf(s[2][r], s[3][r]));
            mt[r] = dppmax<DPP_XOR1>(mt[r]);
            mt[r] = dppmax<DPP_XOR2>(mt[r]);
            mt[r] = dppmax<DPP_HMIR>(mt[r]);
            mt[r] = dppmax<DPP_MIR>(mt[r]);
        }
        float al[4];
#pragma unroll
        for (int r = 0; r < 4; ++r) {
            float mn = fmaxf(mr[r], mt[r]);
            al[r] = exp2f((mr[r] - mn) * SCL);
            mr[r] = mn;
        }
        float rs[4] = {0.f, 0.f, 0.f, 0.f};
#pragma unroll
        for (int jf = 0; jf < 4; ++jf)
#pragma unroll
            for (int r = 0; r < 4; ++r) {
                float p = exp2f((s[jf][r] - mr[r]) * SCL);
                rs[r] += p;
                P[g * 4 + r][jf * 16 + li] = f2bf(p);
            }
#pragma unroll
        for (int r = 0; r < 4; ++r) {
            rs[r] = dppadd<DPP_XOR1>(rs[r]);
            rs[r] = dppadd<DPP_XOR2>(rs[r]);
            rs[r] = dppadd<DPP_HMIR>(rs[r]);
            rs[r] = dppadd<DPP_MIR>(rs[r]);
            lr[r] = lr[r] * al[r] + rs[r];
        }
#pragma unroll
        for (int n = 0; n < 8; ++n)
#pragma unroll
            for (int r = 0; r < 4; ++r) o[n][r] *= al[r];
        asm volatile("s_waitcnt lgkmcnt(0)" ::: "memory");
        __builtin_amdgcn_sched_barrier(0);
#pragma unroll
        for (int kk = 0; kk < 2; ++kk) {
            short8 pa = *(const short8*)&P[li][kk * 32 + g * 8];
#pragma unroll
            for (int n = 0; n < 8; ++n) {
                short8 vfrag = *(const short8*)(vb0 + (size_t)(n * 16 + li) * 2048 + j0 + kk * 32 + g * 8);
                o[n] = __builtin_amdgcn_mfma_f32_16x16x32_bf16(pa, vfrag, o[n], 0, 0, 0);
            }
        }
    }

    __syncthreads();
#pragma unroll
    for (int n = 0; n < 8; ++n)
#pragma unroll
        for (int r = 0; r < 4; ++r)
            oc[wv][g * 4 + r][n * 16 + li] = o[n][r];
    if (li == 0) {
#pragma unroll
        for (int r = 0; r < 4; ++r) {
            ml[wv][g * 4 + r][0] = mr[r];
            ml[wv][g * 4 + r][1] = lr[r];
        }
    }
    __syncthreads();
    float m0 = ml[0][li][0], m1 = ml[1][li][0], m2 = ml[2][li][0], m3 = ml[3][li][0];
    float M = fmaxf(fmaxf(m0, m1), fmaxf(m2, m3));
    float E[4], L = 0.f;
#pragma unroll
    for (int w = 0; w < 4; ++w) {
        E[w] = exp2f((ml[w][li][0] - M) * SCL);
        L += ml[w][li][1] * E[w];
    }
    int c0 = wv * 32 + g * 8;
    float res[8];
#pragma unroll
    for (int c = 0; c < 8; ++c) {
        float a = 0.f;
#pragma unroll
        for (int w = 0; w < 4; ++w) a += oc[w][li][c0 + c] * E[w];
        res[c] = a / L;
    }
    float* op = Out + (size_t)(b * 2048 + r0 + li) * 128 + c0;
    float4 v0 = {res[0], res[1], res[2], res[3]};
    float4 v1 = {res[4], res[5], res[6], res[7]};
    *(float4*)op = v0;
    *(float4*)(op + 4) = v1;
}

extern "C" void kernel_launch(void* const* d_in, const int* in_sizes, int n_in,
                              void* d_out, int out_size, void* d_ws, size_t ws_size,
                              hipStream_t stream) {
    const float* q  = (const float*)d_in[0];
    const float* k  = (const float*)d_in[1];
    const float* v  = (const float*)d_in[2];
    const float* Wq = (const float*)d_in[3];
    const float* Wk = (const float*)d_in[4];
    const float* Wv = (const float*)d_in[5];
    float* Out = (float*)d_out;

    ushort_t* Qb = (ushort_t*)d_ws;          // [16384][128] bf16
    ushort_t* Kb = Qb + 2097152;             // [16384][128] bf16
    ushort_t* Vt = Kb + 2097152;             // [8][128][2048] bf16
    ushort_t* Wt = Vt + 2097152;             // [3][128][1024] bf16

    wt_prep<<<dim3(4, 32, 3), dim3(32, 32), 0, stream>>>(Wq, Wk, Wv, Wt);
    proj_gemm<<<dim3(256, 1, 3), 256, 0, stream>>>(q, k, v, Wt, Qb, Kb, Vt);
    attn_fwd<<<dim3(1024), 256, 0, stream>>>(Qb, Kb, Vt, Out);
}